// Round 10
// baseline (262.888 us; speedup 1.0000x reference)
//
#include <hip/hip_runtime.h>
#include <hip/hip_bf16.h>
#include <stdint.h>

// Problem constants (B,T,D,NH from reference)
#define NHh 16
#define Dm  1024
#define HD  64          // head dim = D/NH
#define Bb  4
#define Tt  4096
#define NCH 128         // chunks along T for the two-pass scans
#define CHL 32          // chunk length (NCH*CHL == Tt)

// 256x256 GEMM tile geometry
#define BM 256
#define BN 256
#define BK 64
#define NKT (Dm / BK)   // 16 K-tiles

using bf16 = __hip_bfloat16;
typedef __attribute__((ext_vector_type(8))) short short8;   // 8 bf16 in 4 VGPRs (MFMA A/B frag)
typedef __attribute__((ext_vector_type(4))) float f32x4;    // MFMA C/D frag

__device__ __forceinline__ float bf2f(bf16 v) { return __bfloat162float(v); }

// bf16 bits -> f32 (exact): bf16 is the high 16 bits of f32
__device__ __forceinline__ float b2f(unsigned short u) {
  union { unsigned int i; float f; } x; x.i = ((unsigned int)u) << 16; return x.f;
}

// fast reciprocal via v_rcp_f32 (~1 ulp; inputs are bf16-derived, tolerance is 1e-2)
__device__ __forceinline__ float frcp(float x) {
  float r; asm("v_rcp_f32 %0, %1" : "=v"(r) : "v"(x)); return r;
}

// async global->LDS, 16B per lane. LDS dest is wave-uniform base + lane*16;
// the GLOBAL source address is PER-LANE (must include the lane offset!).
__device__ __forceinline__ void gld_lds16(const void* g, void* l) {
  __builtin_amdgcn_global_load_lds(
      (const __attribute__((address_space(1))) unsigned int*)g,
      (__attribute__((address_space(3))) unsigned int*)l, 16, 0, 0);
}

// ============== 256x256 GEMM, counted-vmcnt 2-phase pipeline (frozen) ========
template <bool OUT_BF16, bool WRITE_S1>
__global__ __launch_bounds__(512, 2) void gemm256(const bf16* __restrict__ A,
                                                  const bf16* __restrict__ W,
                                                  void* __restrict__ Cout,
                                                  float* __restrict__ S1,
                                                  int M, int N, int K) {
  extern __shared__ char smem[];   // 131072 B: [buf][A 32K | B 32K]
  const int tid  = threadIdx.x;
  const int lane = tid & 63;
  const int wave = tid >> 6;       // 0..7
  const int bid = blockIdx.x;
  const int swz = (bid & 7) * 32 + (bid >> 3);
  const int bn = (swz & 3) * BN;          // N/BN = 4
  const int bm = (swz >> 2) * BM;
  const int wm = (wave >> 1) * 64;        // 4 M bands of 64 rows
  const int wn = (wave & 1) * 128;        // 2 N halves of 128 cols
  const int quad = lane >> 4;
  const int l16  = lane & 15;

  const int srow = wave * 8 + (lane >> 3);               // + n*64
  const int scol = (((lane & 7) ^ (lane >> 3)) << 3);    // elements

  const bf16* Abase = A + (size_t)(bm + srow) * K + scol;
  const bf16* Wbase = W + (size_t)(bn + srow) * K + scol;

  f32x4 acc[4][8] = {};

#define SLAB_A(buf, n) (smem + (buf) * 65536 + (n) * 8192 + wave * 1024)
#define SLAB_B(buf, n) (smem + (buf) * 65536 + 32768 + (n) * 8192 + wave * 1024)
#define STAGE_A(buf, n, k0) gld_lds16(Abase + (size_t)(n) * 64 * K + (k0), SLAB_A(buf, n))
#define STAGE_B(buf, n, k0) gld_lds16(Wbase + (size_t)(n) * 64 * K + (k0), SLAB_B(buf, n))
#define LD_FRAG(base, r, s) (*(const short8*)((base) + (size_t)(r) * 128 + ((((s) ^ ((r) & 7))) << 4)))

  STAGE_A(0, 0, 0); STAGE_A(0, 1, 0); STAGE_A(0, 2, 0); STAGE_A(0, 3, 0);
  STAGE_B(0, 0, 0); STAGE_B(0, 1, 0); STAGE_B(0, 2, 0); STAGE_B(0, 3, 0);
  asm volatile("s_waitcnt vmcnt(0)" ::: "memory");
  __builtin_amdgcn_s_barrier();
  __builtin_amdgcn_sched_barrier(0);

  short8 af[4][2], bfv[4][2];
  for (int t = 0; t < NKT; t++) {
    const int buf = t & 1;
    const char* aL = smem + buf * 65536;
    const char* bL = aL + 32768;
    const int k0n = (t + 1) * BK;
    const bool pf = (t + 1 < NKT);

    if (pf) {
      STAGE_A(buf ^ 1, 0, k0n); STAGE_A(buf ^ 1, 1, k0n);
      STAGE_A(buf ^ 1, 2, k0n); STAGE_A(buf ^ 1, 3, k0n);
      STAGE_B(buf ^ 1, 0, k0n); STAGE_B(buf ^ 1, 2, k0n);
    }
#pragma unroll
    for (int mi = 0; mi < 4; mi++) {
      const int r = wm + mi * 16 + l16;
      af[mi][0] = LD_FRAG(aL, r, quad);
      af[mi][1] = LD_FRAG(aL, r, quad + 4);
    }
#pragma unroll
    for (int nj = 0; nj < 4; nj++) {
      const int r = wn + nj * 16 + l16;
      bfv[nj][0] = LD_FRAG(bL, r, quad);
      bfv[nj][1] = LD_FRAG(bL, r, quad + 4);
    }
    __builtin_amdgcn_s_setprio(1);
#pragma unroll
    for (int mi = 0; mi < 4; mi++)
#pragma unroll
      for (int nj = 0; nj < 4; nj++) {
        acc[mi][nj] = __builtin_amdgcn_mfma_f32_16x16x32_bf16(af[mi][0], bfv[nj][0], acc[mi][nj], 0, 0, 0);
        acc[mi][nj] = __builtin_amdgcn_mfma_f32_16x16x32_bf16(af[mi][1], bfv[nj][1], acc[mi][nj], 0, 0, 0);
      }
    __builtin_amdgcn_s_setprio(0);
    if (pf) { asm volatile("s_waitcnt vmcnt(6)" ::: "memory"); }
    else    { asm volatile("s_waitcnt vmcnt(0)" ::: "memory"); }
    __builtin_amdgcn_s_barrier();
    __builtin_amdgcn_sched_barrier(0);

    if (pf) { STAGE_B(buf ^ 1, 1, k0n); STAGE_B(buf ^ 1, 3, k0n); }
#pragma unroll
    for (int nj = 0; nj < 4; nj++) {
      const int r = wn + 64 + nj * 16 + l16;
      bfv[nj][0] = LD_FRAG(bL, r, quad);
      bfv[nj][1] = LD_FRAG(bL, r, quad + 4);
    }
    __builtin_amdgcn_s_setprio(1);
#pragma unroll
    for (int mi = 0; mi < 4; mi++)
#pragma unroll
      for (int nj = 0; nj < 4; nj++) {
        acc[mi][nj + 4] = __builtin_amdgcn_mfma_f32_16x16x32_bf16(af[mi][0], bfv[nj][0], acc[mi][nj + 4], 0, 0, 0);
        acc[mi][nj + 4] = __builtin_amdgcn_mfma_f32_16x16x32_bf16(af[mi][1], bfv[nj][1], acc[mi][nj + 4], 0, 0, 0);
      }
    __builtin_amdgcn_s_setprio(0);
    asm volatile("s_waitcnt vmcnt(2)" ::: "memory");
    __builtin_amdgcn_s_barrier();
    __builtin_amdgcn_sched_barrier(0);
  }

  if constexpr (OUT_BF16) {
    ushort* cst = (ushort*)smem;
#pragma unroll
    for (int nj = 0; nj < 8; nj++) {
      const int gcol = bn + wn + nj * 16 + l16;
      float ss0 = 0.f, ss1 = 0.f;
#pragma unroll
      for (int mi = 0; mi < 4; mi++) {
        float csum = 0.f;
#pragma unroll
        for (int r = 0; r < 4; r++) {
          const int row = wm + mi * 16 + quad * 4 + r;          // tile-local
          const int col = wn + nj * 16 + l16;                   // tile-local
          const bf16 hv = __float2bfloat16(acc[mi][nj][r]);
          cst[(row * 512 + ((col * 2) ^ ((row & 7) << 4))) >> 1] = __bfloat16_as_ushort(hv);
          if constexpr (WRITE_S1) { const float fv = bf2f(hv); csum += fv * fv; }
        }
        if constexpr (WRITE_S1) { if (mi < 2) ss0 += csum; else ss1 += csum; }
      }
      if constexpr (WRITE_S1) {
        ss0 += __shfl_xor(ss0, 16, 64); ss0 += __shfl_xor(ss0, 32, 64);
        ss1 += __shfl_xor(ss1, 16, 64); ss1 += __shfl_xor(ss1, 32, 64);
        if (quad == 0) {
          const int h = gcol >> 6, d = gcol & 63;
          const int r0 = bm + wm;
          const int b  = r0 >> 12;
          const int c0 = (r0 & (Tt - 1)) >> 5;
          float* s1p = S1 + (((size_t)(b * NHh + h) * NCH) + c0) * HD + d;
          s1p[0]  = ss0;
          s1p[HD] = ss1;
        }
      }
    }
    asm volatile("s_waitcnt lgkmcnt(0)" ::: "memory");
    __builtin_amdgcn_s_barrier();
#pragma unroll
    for (int it = 0; it < 16; it++) {
      const int idx = it * 512 + tid;      // 16B-chunk id (8192 total)
      const int row = idx >> 5;            // 32 chunks per 512B row
      const int ch  = idx & 31;
      const short8 v = *(const short8*)(smem + row * 512 + ((ch ^ (row & 7)) << 4));
      *(short8*)((bf16*)Cout + (size_t)(bm + row) * N + bn + ch * 8) = v;
    }
  } else {
#pragma unroll
    for (int nj = 0; nj < 8; nj++) {
      const int col = bn + wn + nj * 16 + l16;
#pragma unroll
      for (int mi = 0; mi < 4; mi++)
#pragma unroll
        for (int r = 0; r < 4; r++) {
          const int row = bm + wm + mi * 16 + quad * 4 + r;
          ((float*)Cout)[(size_t)row * N + col] = acc[mi][nj][r];
        }
    }
  }
#undef SLAB_A
#undef SLAB_B
#undef STAGE_A
#undef STAGE_B
#undef LD_FRAG
}

// ===== prep: fused {cast x, cast W_attn, cast W_proj, phi->penalty} ==========
__global__ __launch_bounds__(256) void prep(const float* __restrict__ x,
                                            const float* __restrict__ Wa,
                                            const float* __restrict__ Wp,
                                            const float* __restrict__ phi,
                                            bf16* __restrict__ x_bf,
                                            bf16* __restrict__ Wa_bf,
                                            bf16* __restrict__ Wp_bf,
                                            float* __restrict__ penalty) {
  const int bid = blockIdx.x;
  if (bid < 1536) {
    const float* in;
    bf16* out;
    int n, nblk, b0;
    if (bid < 1024)      { in = x;  out = x_bf;  n = Bb * Tt * Dm; nblk = 1024; b0 = 0; }
    else if (bid < 1280) { in = Wa; out = Wa_bf; n = Dm * Dm;      nblk = 256;  b0 = 1024; }
    else                 { in = Wp; out = Wp_bf; n = Dm * Dm;      nblk = 256;  b0 = 1280; }
    const int stride = nblk * 256;
    for (int i = (bid - b0) * 256 + threadIdx.x; i * 4 < n; i += stride) {
      const float4 v = *(const float4*)(in + (size_t)i * 4);
      ushort4 o;
      o.x = __bfloat16_as_ushort(__float2bfloat16(v.x));
      o.y = __bfloat16_as_ushort(__float2bfloat16(v.y));
      o.z = __bfloat16_as_ushort(__float2bfloat16(v.z));
      o.w = __bfloat16_as_ushort(__float2bfloat16(v.w));
      *(ushort4*)(out + (size_t)i * 4) = o;
    }
  } else {
    const int b = bid - 1536;
    const int tid = threadIdx.x;            // 256
    const int lane = tid & 63, wid = tid >> 6;
    __shared__ float wsum[4];
    __shared__ float carry_s;
    if (tid == 0) carry_s = 0.f;
    __syncthreads();
    for (int r = 0; r < Tt / 256; r++) {
      const int t = r * 256 + tid;
      const float v = phi[b * Tt + t];
      float incl = v;
#pragma unroll
      for (int off = 1; off < 64; off <<= 1) {
        float nn = __shfl_up(incl, off, 64);
        if (lane >= off) incl += nn;
      }
      if (lane == 63) wsum[wid] = incl;
      __syncthreads();
      float woff = carry_s;
      for (int wpre = 0; wpre < wid; wpre++) woff += wsum[wpre];
      const float csum = woff + incl;
      const float mean = csum / (float)(t + 1);
      const float dphi = v - mean;
      penalty[b * Tt + t] = dphi * dphi;
      __syncthreads();
      if (tid == 0) carry_s += wsum[0] + wsum[1] + wsum[2] + wsum[3];
      __syncthreads();
    }
  }
}

// ===== mid v2: 1024 threads = 16 heads x 64 lanes (1 d-elem/lane).
// w chunk (64 KB, contiguous) staged to LDS via gld_lds (overlapped with the
// S1-prefix walk); tssa + dots passes read LDS.
__global__ __launch_bounds__(1024, 8) void mid_fused(const bf16* __restrict__ w,
                                                     const float* __restrict__ S1,
                                                     const float* __restrict__ temp,
                                                     const float* __restrict__ gamma,
                                                     const float* __restrict__ penalty,
                                                     float* __restrict__ alpha_f,
                                                     float* __restrict__ S2,
                                                     float* __restrict__ SA) {
  extern __shared__ ushort wlds[];            // [CHL][Dm] ushort = 64 KB
  __shared__ float sm_t[CHL][NHh + 1];
  __shared__ float sm_a[CHL][NHh + 1];
  __shared__ float sm_g[NHh], sm_tv[NHh];
  const int c = blockIdx.x, b = blockIdx.y;
  const int tid = threadIdx.x;
  const int h = tid >> 6, l = tid & 63;       // wave == head

  // stage w chunk: 16 waves x 4 gld_lds(1 KB each) = 64 KB, linear.
  // GLOBAL source is per-lane: include l*16 (round-9 bug fix).
  {
    const char* g = (const char*)(w + ((size_t)(b * Tt + c * CHL)) * Dm) + h * 4096 + l * 16;
    char* d = (char*)wlds + h * 4096;
    gld_lds16(g, d); gld_lds16(g + 1024, d + 1024);
    gld_lds16(g + 2048, d + 2048); gld_lds16(g + 3072, d + 3072);
  }
  if (tid < NHh) { sm_g[tid] = gamma[tid]; sm_tv[tid] = temp[tid]; }

  // S1 exclusive prefix for own column d=l (4 B loads, 256 B/wave), 4-deep ILP
  const float* p = S1 + ((size_t)(b * NHh + h) * NCH) * HD + l;
  float s0 = 0.f, s1 = 0.f, s2 = 0.f, s3 = 0.f;
  int cc = 0;
  for (; cc + 4 <= c; cc += 4) {
    s0 += p[(size_t)cc * HD];       s1 += p[(size_t)(cc + 1) * HD];
    s2 += p[(size_t)(cc + 2) * HD]; s3 += p[(size_t)(cc + 3) * HD];
  }
  for (; cc < c; cc++) s0 += p[(size_t)cc * HD];
  float a = s0 + s1 + s2 + s3;

  asm volatile("s_waitcnt vmcnt(0)" ::: "memory");
  __syncthreads();

  const float tv = sm_tv[h];
  const int col = h * 64 + l;
  // pass 1: tssa
#pragma unroll 4
  for (int i = 0; i < CHL; i++) {
    const float f = b2f(wlds[i * Dm + col]);
    const float q = f * f;
    a += q;
    float val = q * frcp(fmaxf(a, 1e-12f));
    val += __shfl_xor(val, 1, 64);
    val += __shfl_xor(val, 2, 64);
    val += __shfl_xor(val, 4, 64);
    val += __shfl_xor(val, 8, 64);
    val += __shfl_xor(val, 16, 64);
    val += __shfl_xor(val, 32, 64);
    if (l == 0) sm_t[i][h] = tv * val;
  }
  __syncthreads();

  // softmax over heads (threads 0..31, one t each)
  if (tid < CHL) {
    const int t = tid;
    const float pen = penalty[(size_t)b * Tt + c * CHL + t];
    float sc[NHh];
    float mx = -1e30f;
#pragma unroll
    for (int hh = 0; hh < NHh; hh++) {
      sc[hh] = sm_t[t][hh] - sm_g[hh] * pen;
      mx = fmaxf(mx, sc[hh]);
    }
    float sum = 0.f;
#pragma unroll
    for (int hh = 0; hh < NHh; hh++) { const float e = __expf(sc[hh] - mx); sc[hh] = e; sum += e; }
    const float inv = 1.f / sum;
#pragma unroll
    for (int hh = 0; hh < NHh; hh++) sm_a[t][hh] = sc[hh] * inv;
  }
  __syncthreads();

  // alpha out: per head, lanes 0..31 write 32 consecutive floats
  if (l < CHL) alpha_f[((size_t)(b * NHh + h)) * Tt + c * CHL + l] = sm_a[l][h];

  // pass 2: dots chunk sums from LDS
  float dsum = 0.f, sa = 0.f;
#pragma unroll 4
  for (int i = 0; i < CHL; i++) {
    const float al = sm_a[i][h];
    const float f = b2f(wlds[i * Dm + col]);
    dsum += f * f * al;
    sa += al;
  }
  S2[(((size_t)(b * NHh + h) * NCH) + c) * HD + l] = dsum;
  if (l == 0) SA[(size_t)(b * NHh + h) * NCH + c] = sa;
}

// ===== y v2: 1024 threads = 16 heads x 64 lanes (1 d-elem/lane).
__global__ __launch_bounds__(1024, 8) void y_phase3(const bf16* __restrict__ w,
                                                    const float* __restrict__ alpha_f,
                                                    const float* __restrict__ S2,
                                                    const float* __restrict__ SA,
                                                    bf16* __restrict__ yprime) {
  extern __shared__ ushort wlds[];            // 64 KB
  __shared__ float sm_al[NHh][CHL];
  const int c = blockIdx.x, b = blockIdx.y;
  const int tid = threadIdx.x;
  const int h = tid >> 6, l = tid & 63;

  // stage w chunk (per-lane global source: + l*16 — round-9 bug fix)
  {
    const char* g = (const char*)(w + ((size_t)(b * Tt + c * CHL)) * Dm) + h * 4096 + l * 16;
    char* d = (char*)wlds + h * 4096;
    gld_lds16(g, d); gld_lds16(g + 1024, d + 1024);
    gld_lds16(g + 2048, d + 2048); gld_lds16(g + 3072, d + 3072);
  }
  // stage alpha 16x32 (threads 0..511)
  if (tid < NHh * CHL) {
    const int h2 = tid >> 5, t = tid & 31;
    sm_al[h2][t] = alpha_f[((size_t)(b * NHh + h2)) * Tt + c * CHL + t];
  }

  // SA exclusive prefix: lanes split chunks, 6-step reduce -> uniform
  const float* sap = SA + (size_t)(b * NHh + h) * NCH;
  float sa_part = 0.f;
  for (int cc = l; cc < c; cc += 64) sa_part += sap[cc];
  sa_part += __shfl_xor(sa_part, 1, 64);
  sa_part += __shfl_xor(sa_part, 2, 64);
  sa_part += __shfl_xor(sa_part, 4, 64);
  sa_part += __shfl_xor(sa_part, 8, 64);
  sa_part += __shfl_xor(sa_part, 16, 64);
  sa_part += __shfl_xor(sa_part, 32, 64);
  float acca = sa_part;

  // S2 exclusive prefix for own column d=l, 4-deep ILP
  const float* p = S2 + ((size_t)(b * NHh + h) * NCH) * HD + l;
  float s0 = 0.f, s1 = 0.f, s2 = 0.f, s3 = 0.f;
  int cc = 0;
  for (; cc + 4 <= c; cc += 4) {
    s0 += p[(size_t)cc * HD];       s1 += p[(size_t)(cc + 1) * HD];
    s2 += p[(size_t)(cc + 2) * HD]; s3 += p[(size_t)(cc + 3) * HD];
  }
  for (; cc < c; cc++) s0 += p[(size_t)cc * HD];
  float a = s0 + s1 + s2 + s3;

  asm volatile("s_waitcnt vmcnt(0)" ::: "memory");
  __syncthreads();

  const int col = h * 64 + l;
  bf16* yp = yprime + ((size_t)(b * Tt + c * CHL)) * Dm + col;
#pragma unroll 4
  for (int i = 0; i < CHL; i++) {
    const float al = sm_al[h][i];
    const float f = b2f(wlds[i * Dm + col]);
    a += f * f * al;
    acca += al;
    const float rinv = frcp(acca + 1e-8f);
    const float attn = fminf(frcp(1.f + a * rinv), 10000.f);
    yp[(size_t)i * Dm] = __float2bfloat16(-f * al * attn);
  }
}

extern "C" void kernel_launch(void* const* d_in, const int* in_sizes, int n_in,
                              void* d_out, int out_size, void* d_ws, size_t ws_size,
                              hipStream_t stream) {
  const float* x     = (const float*)d_in[0];
  const float* phi   = (const float*)d_in[1];
  const float* Wattn = (const float*)d_in[2];
  const float* Wproj = (const float*)d_in[3];
  const float* gamma = (const float*)d_in[4];
  const float* temp  = (const float*)d_in[5];

  float* y_out    = (float*)d_out;                          // (B,T,D) fp32
  float* alpha_f  = y_out + (size_t)Bb * Tt * Dm;           // (B,NH,T) fp32

  char* ws = (char*)d_ws;
  bf16*  x_bf   = (bf16*)ws;  ws += (size_t)Bb * Tt * Dm * 2;         // 32 MB
  bf16*  Wa_bf  = (bf16*)ws;  ws += (size_t)Dm * Dm * 2;              // 2 MB
  bf16*  Wp_bf  = (bf16*)ws;  ws += (size_t)Dm * Dm * 2;              // 2 MB
  bf16*  w_bf   = (bf16*)ws;  ws += (size_t)Bb * Tt * Dm * 2;         // 32 MB
  float* pen    = (float*)ws; ws += (size_t)Bb * Tt * 4;              // 64 KB
  float* S1     = (float*)ws; ws += (size_t)Bb * NHh * NCH * HD * 4;  // 2 MB (raw)
  float* S2     = (float*)ws; ws += (size_t)Bb * NHh * NCH * HD * 4;  // 2 MB (raw)
  float* SA     = (float*)ws; ws += (size_t)Bb * NHh * NCH * 4;       // 32 KB (raw)
  bf16*  yprime = x_bf;  // alias: x_bf is dead after GEMM1

  static int attr_done = 0;
  if (!attr_done) {
    hipFuncSetAttribute((const void*)gemm256<true, true>,
                        hipFuncAttributeMaxDynamicSharedMemorySize, 131072);
    hipFuncSetAttribute((const void*)gemm256<false, false>,
                        hipFuncAttributeMaxDynamicSharedMemorySize, 131072);
    hipFuncSetAttribute((const void*)mid_fused,
                        hipFuncAttributeMaxDynamicSharedMemorySize, 65536);
    hipFuncSetAttribute((const void*)y_phase3,
                        hipFuncAttributeMaxDynamicSharedMemorySize, 65536);
    attr_done = 1;
  }

  const int M = Bb * Tt, N = Dm, K = Dm;
  dim3 gg((M / BM) * (N / BN)), gb(512);

  prep<<<dim3(1540), dim3(256), 0, stream>>>(x, Wattn, Wproj, phi, x_bf, Wa_bf, Wp_bf, pen);
  gemm256<true, true><<<gg, gb, 131072, stream>>>(x_bf, Wa_bf, (void*)w_bf, S1, M, N, K);
  mid_fused<<<dim3(NCH, Bb), dim3(1024), 65536, stream>>>(w_bf, S1, temp, gamma, pen,
                                                          alpha_f, S2, SA);
  y_phase3<<<dim3(NCH, Bb), dim3(1024), 65536, stream>>>(w_bf, alpha_f, S2, SA, yprime);
  gemm256<false, false><<<gg, gb, 131072, stream>>>(yprime, Wp_bf, (void*)y_out, nullptr, M, N, K);
}